// Round 3
// baseline (733.710 us; speedup 1.0000x reference)
//
#include <hip/hip_runtime.h>

// Problem constants: B=2, S=2048 -> T=4096 tokens; D=1024, H=4096, E=8, top-2.
#define T_TOK 4096
#define DIM   1024
#define HID   4096
#define NEXP  8
#define MAXROWS 9216

typedef unsigned short u16;
typedef __attribute__((ext_vector_type(8))) short short8;   // 8 bf16 (4 VGPRs) MFMA frag
typedef __attribute__((ext_vector_type(4))) float f32x4;
typedef __attribute__((ext_vector_type(2))) unsigned short u16x2;
typedef __attribute__((ext_vector_type(4))) unsigned short u16x4;
typedef __attribute__((ext_vector_type(8))) unsigned short u16x8;

typedef __attribute__((address_space(3))) unsigned int lds_uint;
typedef __attribute__((address_space(3))) u16 lds_u16;
typedef const __attribute__((address_space(1))) unsigned int gbl_uint;

__device__ __forceinline__ u16 f2bf(float f) {
    union { float f; unsigned int u; } v; v.f = f;
    unsigned int r = v.u + 0x7fffu + ((v.u >> 16) & 1u);   // RNE
    return (u16)(r >> 16);
}

// fast gelu (tanh form): max |err| vs exact erf-gelu ~3e-4, well under budget
__device__ __forceinline__ float gelu_f(float v) {
    float u = 1.5957691216f * (v + 0.044715f * v * v * v);   // 2*0.7978845608*(...)
    float s = 1.0f / (1.0f + __expf(-u));                    // sigmoid(2u') == 0.5*(1+tanh(u'))
    return v * s;
}

// asm ds_read_b128: invisible to compiler memory model -> no auto vmcnt(0) drain
// before LDS reads of global_load_lds-written data (rule 18 / m201 pattern).
// MUST be followed by s_waitcnt lgkmcnt(0) + sched_barrier(0) before consuming.
__device__ __forceinline__ short8 ds_read128(unsigned byte_addr) {
    short8 r;
    asm volatile("ds_read_b128 %0, %1" : "=v"(r) : "v"(byte_addr));
    return r;
}

// ---------------- fused transpose+cast for BOTH weights; also zeroes counts.
// fp32 [R][C] -> bf16 [C][R] per expert. 128x128 tiles (load segs 512B, store segs 256B).
// blockIdx.x in [0,4096): first 2048 blocks w1 (R=1024,C=4096); rest w2 (R=4096,C=1024).
__global__ __launch_bounds__(256)
void transpose_cast2(const float* __restrict__ w1, u16* __restrict__ w1t,
                     const float* __restrict__ w2, u16* __restrict__ w2t,
                     int* __restrict__ counts) {
    int b = blockIdx.x;
    if (b == 0 && threadIdx.x < NEXP) counts[threadIdx.x] = 0;
    const float* in; u16* out; int R, C, bx, by, e;
    if (b < 2048) {
        e = b >> 8; int t = b & 255; bx = t & 31; by = t >> 5;   // 32 x (C/128), 8 y (R/128)
        in = w1; out = w1t; R = DIM; C = HID;
    } else {
        b -= 2048;
        e = b >> 8; int t = b & 255; bx = t & 7; by = t >> 3;    // 8 x, 32 y
        in = w2; out = w2t; R = HID; C = DIM;
    }
    __shared__ u16 tl[128 * 130];    // stride 130 u16: 4B-aligned, breaks pow2 banks
    size_t mo = (size_t)e * DIM * HID;
    const float* ip = in + mo;
    u16* op = out + mo;
    int c0 = bx * 128, r0 = by * 128;
    int tid = threadIdx.x;
#pragma unroll
    for (int j = 0; j < 16; ++j) {
        int id = tid + 256 * j;
        int r = id >> 5, cg = id & 31;                           // row, 16B col-group
        f32x4 v = *(const f32x4*)(ip + (size_t)(r0 + r) * C + c0 + 4 * cg);
        u16x2 wa; wa.x = f2bf(v.x); wa.y = f2bf(v.y);
        u16x2 wb; wb.x = f2bf(v.z); wb.y = f2bf(v.w);
        *(u16x2*)(tl + r * 130 + 4 * cg)     = wa;
        *(u16x2*)(tl + r * 130 + 4 * cg + 2) = wb;
    }
    __syncthreads();
#pragma unroll
    for (int j = 0; j < 8; ++j) {
        int id = tid + 256 * j;
        int c = id >> 4, ch = id & 15;                           // out row, 16B chunk
        u16x8 o;
#pragma unroll
        for (int k = 0; k < 8; ++k) o[k] = tl[(ch * 8 + k) * 130 + c];
        *(u16x8*)(op + (size_t)(c0 + c) * R + r0 + ch * 8) = o;
    }
}

// ---------------- router: logits -> softmax -> top2 -> renormalized gates
__global__ __launch_bounds__(256)
void router_k(const float* __restrict__ x, const float* __restrict__ rw,
              int* __restrict__ counts, int* __restrict__ tE,
              int* __restrict__ tS, float* __restrict__ tG) {
    int wave = threadIdx.x >> 6, lane = threadIdx.x & 63;
    int t = blockIdx.x * 4 + wave;
    const float* xr = x + (size_t)t * DIM;
    float xv[16];
#pragma unroll
    for (int i = 0; i < 16; ++i) xv[i] = xr[lane + 64*i];
    float lg[NEXP];
#pragma unroll
    for (int e = 0; e < NEXP; ++e) {
        const float* wr_ = rw + e * DIM;
        float a = 0.f;
#pragma unroll
        for (int i = 0; i < 16; ++i) a += xv[i] * wr_[lane + 64*i];
        lg[e] = a;
    }
#pragma unroll
    for (int off = 32; off > 0; off >>= 1)
#pragma unroll
        for (int e = 0; e < NEXP; ++e) lg[e] += __shfl_xor(lg[e], off, 64);
    if (lane == 0) {
        float mx = lg[0];
        for (int e = 1; e < NEXP; ++e) mx = fmaxf(mx, lg[e]);
        float p[NEXP], s = 0.f;
        for (int e = 0; e < NEXP; ++e) { p[e] = expf(lg[e] - mx); s += p[e]; }
        float inv_s = 1.f / s;
        for (int e = 0; e < NEXP; ++e) p[e] *= inv_s;
        int i0 = 0;
        for (int e = 1; e < NEXP; ++e) if (p[e] > p[i0]) i0 = e;
        int i1 = (i0 == 0) ? 1 : 0;
        for (int e = 0; e < NEXP; ++e) if (e != i0 && p[e] > p[i1]) i1 = e;
        float v0 = p[i0], v1 = p[i1];
        float inv = 1.f / (v0 + v1 + 1e-9f);
        int s0 = atomicAdd(&counts[i0], 1);
        int s1 = atomicAdd(&counts[i1], 1);
        tE[2*t] = i0;  tE[2*t+1] = i1;
        tS[2*t] = s0;  tS[2*t+1] = s1;
        tG[2*t] = v0 * inv;  tG[2*t+1] = v1 * inv;
    }
}

// inline exclusive scan of 128-padded counts: returns base for expert e
__device__ __forceinline__ int pbase_of(const int* __restrict__ counts, int e) {
    int pb = 0;
#pragma unroll
    for (int i = 0; i < NEXP; ++i) {
        int pad = ((counts[i] + 127) >> 7) << 7;
        pb += (i < e) ? pad : 0;
    }
    return pb;
}

// ---------------- gather x rows (fp32) into packed bf16 rows per assignment
__global__ __launch_bounds__(256)
void gather_k(const float* __restrict__ x, const int* __restrict__ tE,
              const int* __restrict__ tS, const int* __restrict__ counts,
              u16* __restrict__ xg) {
    int a = blockIdx.x;              // 0..8191
    int t = a >> 1, k = a & 1;
    int e = tE[2*t + k];
    int row = pbase_of(counts, e) + tS[2*t + k];
    const f32x4* xr = (const f32x4*)(x + (size_t)t * DIM);
    u16x4* o = (u16x4*)(xg + (size_t)row * DIM);
    int i = threadIdx.x;             // 256 threads x 4 floats = 1024
    f32x4 v = xr[i];
    u16x4 r; r.x = f2bf(v.x); r.y = f2bf(v.y); r.z = f2bf(v.z); r.w = f2bf(v.w);
    o[i] = r;
}

// ---------------- grouped GEMM: C[row][col] = A[row][K_sub] * Bt[col][K_sub]  (per expert)
// 256x256 tile, BK=64, 8 waves (2Mx4N), double-buffered LDS (128 KiB).
// T4 counted-vmcnt pipeline with ASM ds_reads (rule 18): LDS fragment reads are
// inline-asm ds_read_b128, so the compiler's alias analysis never inserts a
// vmcnt(0) drain before them -> the 8 loads staged for tile t+1 genuinely stay
// in flight across tile t's compute. Data-ready fencing is manual:
// s_waitcnt lgkmcnt(0) + sched_barrier(0) before each MFMA cluster.
// T1 expert-per-XCD swizzle: each XCD walks one expert, B-slice+A L2-resident
// (verified round 2: FETCH 210->59 MB). XOR-swizzled 16B LDS chunks (0 conflicts).
template<int K, int KSPLIT, int NX, bool GELU, typename OutT>
__global__ __launch_bounds__(512, 2)
void gemm_bt(const u16* __restrict__ A, const u16* __restrict__ BtAll,
             OutT* __restrict__ C, const int* __restrict__ counts,
             int N, size_t cstride) {
    // bijective XCD swizzle (grid % 8 == 0), then decompose y(row)-fastest
    int bid = blockIdx.x;
    constexpr int NWG = NX * 16 * NEXP * KSPLIT;
    int swz = (bid & 7) * (NWG / 8) + (bid >> 3);
    int mt = swz & 15;
    int tmp = swz >> 4;
    int xb, z;
    if constexpr (NX == 16) { xb = tmp & 15; z = tmp >> 4; }
    else                    { xb = tmp & 3;  z = tmp >> 2; }
    int e  = z / KSPLIT;
    int ks = z % KSPLIT;
    int cnt = counts[e];
    if (mt * 256 >= cnt) return;
    int row0 = pbase_of(counts, e) + mt * 256;
    int limit = cnt - mt * 256;          // valid rows in this block (BM=256 > 128 pad)
    const u16* Bt = BtAll + (size_t)e * N * K;
    OutT* Cp = C + (size_t)ks * cstride;
    int col0 = xb * 256;
    const int kb0 = ks * (K / KSPLIT);
    constexpr int NT = K / KSPLIT / 64;  // K-tiles

    // 128 KiB: A0 [0,16K) A1 [16K,32K) B0 [32K,48K) B1 [48K,64K) in u16 units
    __shared__ __align__(16) u16 smem[65536];

    int tid = threadIdx.x;
    int lane = tid & 63;
    int w = tid >> 6;                    // 0..7
    int quad = lane >> 4, m16 = lane & 15;
    int wr = (w >> 2) * 128, wc = (w & 3) * 64;   // wave's output sub-tile origin
    int rsub = lane >> 3;                // 0..7: row within an 8-row staging group
    int kch  = lane & 7;                 // 16B chunk within row (LDS slot)
    int kchs = kch ^ rsub;               // swizzled GLOBAL chunk fetched into that slot

    // staging pointers (bumped +64 elem = 128 B per K-tile); A rows clamped to ws
    const u16* ga[4];
    const u16* gb[4];
#pragma unroll
    for (int i = 0; i < 4; ++i) {
        int g = (w << 2) + i;
        int ra = row0 + g * 8 + rsub;
        if (ra > MAXROWS - 1) ra = MAXROWS - 1;      // tile may overhang padded rows
        ga[i] = A  + (size_t)ra * K + kb0 + kchs * 8;
        gb[i] = Bt + (size_t)(col0 + g * 8 + rsub) * K + kb0 + kchs * 8;
    }
    // fragment LDS byte addresses: row&7 == m16&7 for all frags (16 | row steps)
    int sw = m16 & 7;
    unsigned smb = (unsigned)(size_t)(lds_u16*)smem;
    unsigned aLo = smb + (unsigned)(((wr + m16) * 64 + ((quad       ^ sw) << 3)) * 2);
    unsigned aHi = smb + (unsigned)(((wr + m16) * 64 + (((4 + quad) ^ sw) << 3)) * 2);
    unsigned bLo = smb + 65536u + (unsigned)(((wc + m16) * 64 + ((quad       ^ sw) << 3)) * 2);
    unsigned bHi = smb + 65536u + (unsigned)(((wc + m16) * 64 + (((4 + quad) ^ sw) << 3)) * 2);

    f32x4 acc[8][4] = {};

    // prologue: issue K-tile 0 stage into buf 0 (no wait here — pipeline fills)
#pragma unroll
    for (int i = 0; i < 4; ++i) {
        int g = (w << 2) + i;
        __builtin_amdgcn_global_load_lds((gbl_uint*)ga[i], (lds_uint*)(smem + g * 512), 16, 0, 0);
        __builtin_amdgcn_global_load_lds((gbl_uint*)gb[i], (lds_uint*)(smem + 32768 + g * 512), 16, 0, 0);
        ga[i] += 64; gb[i] += 64;
    }

#pragma unroll 2
    for (int t = 0; t < NT; ++t) {
        unsigned db = (unsigned)(t & 1) * 32768u;    // double-buffer byte offset
        // barrier1: all waves done reading buf (t-1)&1 -> safe to overwrite
        __builtin_amdgcn_s_barrier();
        if (t + 1 < NT) {
#pragma unroll
            for (int i = 0; i < 4; ++i) {
                int g = (w << 2) + i;
                __builtin_amdgcn_global_load_lds((gbl_uint*)ga[i],
                    (lds_uint*)(smem + ((t + 1) & 1) * 16384 + g * 512), 16, 0, 0);
                __builtin_amdgcn_global_load_lds((gbl_uint*)gb[i],
                    (lds_uint*)(smem + 32768 + ((t + 1) & 1) * 16384 + g * 512), 16, 0, 0);
                ga[i] += 64; gb[i] += 64;
            }
            // wait current tile's 8 loads only; the 8 just issued stay in flight
            asm volatile("s_waitcnt vmcnt(8)" ::: "memory");
        } else {
            asm volatile("s_waitcnt vmcnt(0)" ::: "memory");
        }
        // barrier2: tile t staged data visible to all waves
        __builtin_amdgcn_s_barrier();
        __builtin_amdgcn_sched_barrier(0);

        short8 a0[4], a1[4], b0[4], b1[4];
        // ---- P1: asm-read A m0-3 (lo/hi kstep) + B n0-3; fence; 32 MFMA
#pragma unroll
        for (int m = 0; m < 4; ++m) {
            a0[m] = ds_read128(aLo + db + m * 2048);
            a1[m] = ds_read128(aHi + db + m * 2048);
        }
#pragma unroll
        for (int n = 0; n < 4; ++n) {
            b0[n] = ds_read128(bLo + db + n * 2048);
            b1[n] = ds_read128(bHi + db + n * 2048);
        }
        asm volatile("s_waitcnt lgkmcnt(0)" ::: "memory");
        __builtin_amdgcn_sched_barrier(0);
        __builtin_amdgcn_s_setprio(1);
#pragma unroll
        for (int m = 0; m < 4; ++m)
#pragma unroll
            for (int n = 0; n < 4; ++n) {
                acc[m][n] = __builtin_amdgcn_mfma_f32_16x16x32_bf16(a0[m], b0[n], acc[m][n], 0, 0, 0);
                acc[m][n] = __builtin_amdgcn_mfma_f32_16x16x32_bf16(a1[m], b1[n], acc[m][n], 0, 0, 0);
            }
        __builtin_amdgcn_s_setprio(0);
        __builtin_amdgcn_sched_barrier(0);
        // ---- P2: asm-read A m4-7 (reuse regs); fence; 32 MFMA
#pragma unroll
        for (int m = 0; m < 4; ++m) {
            a0[m] = ds_read128(aLo + db + (4 + m) * 2048);
            a1[m] = ds_read128(aHi + db + (4 + m) * 2048);
        }
        asm volatile("s_waitcnt lgkmcnt(0)" ::: "memory");
        __builtin_amdgcn_sched_barrier(0);
        __builtin_amdgcn_s_setprio(1);
#pragma unroll
        for (int m = 0; m < 4; ++m)
#pragma unroll
            for (int n = 0; n < 4; ++n) {
                acc[4 + m][n] = __builtin_amdgcn_mfma_f32_16x16x32_bf16(a0[m], b0[n], acc[4 + m][n], 0, 0, 0);
                acc[4 + m][n] = __builtin_amdgcn_mfma_f32_16x16x32_bf16(a1[m], b1[n], acc[4 + m][n], 0, 0, 0);
            }
        __builtin_amdgcn_s_setprio(0);
        __builtin_amdgcn_sched_barrier(0);
    }

    // epilogue: C/D layout col=lane&15, row=quad*4+reg (verified mapping)
    if (GELU) {
        // __syncthreads: all waves past their lgkmcnt(0) -> asm reads complete;
        // full compiler memory barrier -> epilogue smem stores can't hoist above
        __syncthreads();
        // stage bf16 256x256 tile in LDS (XOR-swizzled 16B chunks), coalesced u16x8 stores
#pragma unroll
        for (int mi = 0; mi < 8; ++mi) {
#pragma unroll
            for (int r = 0; r < 4; ++r) {
                int row = wr + mi * 16 + quad * 4 + r;
#pragma unroll
                for (int ni = 0; ni < 4; ++ni) {
                    int col = wc + ni * 16 + m16;
                    int ch = col >> 3, w8 = col & 7;
                    smem[row * 256 + (((ch ^ (row & 31)) << 3) | w8)] = f2bf(gelu_f(acc[mi][ni][r]));
                }
            }
        }
        __syncthreads();
        int rr = tid >> 5, ch = tid & 31;
#pragma unroll
        for (int it = 0; it < 16; ++it) {
            int row = it * 16 + rr;
            if (row < limit) {
                u16x8 v = *(const u16x8*)(smem + row * 256 + ((ch ^ (row & 31)) << 3));
                *(u16x8*)((u16*)Cp + (size_t)(row0 + row) * N + col0 + ch * 8) = v;
            }
        }
    } else {
#pragma unroll
        for (int mi = 0; mi < 8; ++mi)
#pragma unroll
            for (int r = 0; r < 4; ++r) {
                int rl = wr + mi * 16 + quad * 4 + r;
                if (rl < limit) {
                    float* rp = (float*)Cp + (size_t)(row0 + rl) * N + col0 + wc + m16;
#pragma unroll
                    for (int ni = 0; ni < 4; ++ni)
                        rp[ni * 16] = acc[mi][ni][r];
                }
            }
    }
}

// ---------------- combine: out[t] = g0*(p0+p1)[row0(t)] + g1*(p0+p1)[row1(t)]
__global__ __launch_bounds__(256)
void combine_k(const float* __restrict__ p0, const float* __restrict__ p1,
               const int* __restrict__ tE, const int* __restrict__ tS,
               const float* __restrict__ tG, const int* __restrict__ counts,
               float* __restrict__ out) {
    int t = blockIdx.x;
    int e0 = tE[2*t], e1 = tE[2*t+1];
    int r0 = pbase_of(counts, e0) + tS[2*t];
    int r1 = pbase_of(counts, e1) + tS[2*t+1];
    float g0 = tG[2*t], g1 = tG[2*t+1];
    int i = threadIdx.x;
    f32x4 a0 = ((const f32x4*)(p0 + (size_t)r0 * DIM))[i];
    f32x4 b0 = ((const f32x4*)(p1 + (size_t)r0 * DIM))[i];
    f32x4 a1 = ((const f32x4*)(p0 + (size_t)r1 * DIM))[i];
    f32x4 b1 = ((const f32x4*)(p1 + (size_t)r1 * DIM))[i];
    f32x4* o = (f32x4*)(out + (size_t)t * DIM);
    o[i] = g0 * (a0 + b0) + g1 * (a1 + b1);
}

extern "C" void kernel_launch(void* const* d_in, const int* in_sizes, int n_in,
                              void* d_out, int out_size, void* d_ws, size_t ws_size,
                              hipStream_t stream) {
    const float* x  = (const float*)d_in[0];   // [4096,1024]
    const float* rw = (const float*)d_in[1];   // [8,1024]
    const float* w1 = (const float*)d_in[2];   // [8,1024,4096]
    const float* w2 = (const float*)d_in[3];   // [8,4096,1024]
    float* out = (float*)d_out;

    char* ws = (char*)d_ws;
    // layout (bytes):
    u16* w1t = (u16*)(ws + 0);                 // bf16 [E][H][D]   67,108,864
    u16* xg  = (u16*)(ws + 67108864ull);       // bf16 [9216][D]   18,874,368 -> 85,983,232
    u16* w2t = (u16*)(ws + 85983232ull);       // bf16 [E][D][H]   67,108,864 -> 153,092,096
    u16* hb  = (u16*)(ws + 153092096ull);      // bf16 [9216][H]   75,497,472 -> 228,589,568
    // fc2 split-K partials alias w1t+xg (dead after fc1): 2 x 37,748,736 = 75,497,472 <= 85,983,232
    float* p0 = (float*)(ws + 0);
    float* p1 = (float*)(ws + 37748736ull);
    int* ctrl   = (int*)(ws + 228589568ull);
    int* counts = ctrl;            // 8
    int* tE     = ctrl + 32;       // 8192
    int* tS     = ctrl + 32 + 8192;
    float* tG   = (float*)(ctrl + 32 + 16384);

    // fused transposes (+ counts zeroing, block 0)
    transpose_cast2<<<4096, 256, 0, stream>>>(w1, w1t, w2, w2t, counts);
    router_k<<<T_TOK / 4, 256, 0, stream>>>(x, rw, counts, tE, tS, tG);
    gather_k<<<T_TOK * 2, 256, 0, stream>>>(x, tE, tS, counts, xg);
    // fc1 + gelu: [rows x 1024] @ [1024 x 4096] -> hb (bf16). 1D grid 16x16x8 = 2048.
    gemm_bt<DIM, 1, 16, true, u16><<<2048, 512, 0, stream>>>(
        xg, w1t, hb, counts, HID, 0);
    // fc2 split-K=2: [rows x 4096] @ [4096 x 1024] -> p0/p1 (f32). 1D grid 4x16x16 = 1024.
    gemm_bt<HID, 2, 4, false, float><<<1024, 512, 0, stream>>>(
        hb, w2t, p0, counts, DIM, (size_t)MAXROWS * DIM);
    combine_k<<<T_TOK, 256, 0, stream>>>(p0, p1, tE, tS, tG, counts, out);
}

// Round 4
// 670.723 us; speedup vs baseline: 1.0939x; 1.0939x over previous
//
#include <hip/hip_runtime.h>

// Problem constants: B=2, S=2048 -> T=4096 tokens; D=1024, H=4096, E=8, top-2.
#define T_TOK 4096
#define DIM   1024
#define HID   4096
#define NEXP  8
#define MAXROWS 9216

typedef unsigned short u16;
typedef __attribute__((ext_vector_type(8))) short short8;   // 8 bf16 (4 VGPRs) MFMA frag
typedef __attribute__((ext_vector_type(4))) float f32x4;
typedef __attribute__((ext_vector_type(4))) unsigned short u16x4;
typedef __attribute__((ext_vector_type(8))) unsigned short u16x8;

typedef __attribute__((address_space(3))) unsigned int lds_uint;
typedef const __attribute__((address_space(1))) unsigned int gbl_uint;

__device__ __forceinline__ u16 f2bf(float f) {
    union { float f; unsigned int u; } v; v.f = f;
    unsigned int r = v.u + 0x7fffu + ((v.u >> 16) & 1u);   // RNE
    return (u16)(r >> 16);
}

// fast gelu (tanh form): max |err| vs exact erf-gelu ~3e-4, well under budget
__device__ __forceinline__ float gelu_f(float v) {
    float u = 1.5957691216f * (v + 0.044715f * v * v * v);   // 2*0.7978845608*(...)
    float s = 1.0f / (1.0f + __expf(-u));                    // sigmoid(2u') == 0.5*(1+tanh(u'))
    return v * s;
}

// ---------------- fused transpose+cast for BOTH weights; also zeroes counts.
// fp32 [R][C] -> bf16 [C][R] per expert. blockIdx.x in [0,16384):
// first 8192 blocks: w1 (R=1024,C=4096); rest: w2 (R=4096,C=1024).
__global__ __launch_bounds__(256)
void transpose_cast2(const float* __restrict__ w1, u16* __restrict__ w1t,
                     const float* __restrict__ w2, u16* __restrict__ w2t,
                     int* __restrict__ counts) {
    int b = blockIdx.x;
    if (b == 0 && threadIdx.x < NEXP) counts[threadIdx.x] = 0;
    const float* in; u16* out; int R, C, bx, by, e;
    if (b < 8192) {
        e = b >> 10; int t = b & 1023; bx = t & 63; by = t >> 6;   // 64 x, 16 y
        in = w1; out = w1t; R = DIM; C = HID;
    } else {
        b -= 8192;
        e = b >> 10; int t = b & 1023; bx = t & 15; by = t >> 4;   // 16 x, 64 y
        in = w2; out = w2t; R = HID; C = DIM;
    }
    __shared__ u16 t[64 * 68];    // stride 68 u16 keeps 8B alignment, breaks pow2 banks
    size_t mo = (size_t)e * DIM * HID;
    const float* ip = in + mo;
    u16* op = out + mo;
    int c0 = bx * 64, r0 = by * 64;
    int tid = threadIdx.x;
#pragma unroll
    for (int j = 0; j < 4; ++j) {
        int id = tid + 256 * j;
        int r = id >> 4, cc = id & 15;
        f32x4 v = *(const f32x4*)(ip + (size_t)(r0 + r) * C + c0 + 4 * cc);
        u16x4 w; w.x = f2bf(v.x); w.y = f2bf(v.y); w.z = f2bf(v.z); w.w = f2bf(v.w);
        *(u16x4*)(t + r * 68 + 4 * cc) = w;
    }
    __syncthreads();
#pragma unroll
    for (int j = 0; j < 4; ++j) {
        int id = tid + 256 * j;
        int c = id >> 4, rj = id & 15;
        u16x4 o;
        o.x = t[(4 * rj + 0) * 68 + c];
        o.y = t[(4 * rj + 1) * 68 + c];
        o.z = t[(4 * rj + 2) * 68 + c];
        o.w = t[(4 * rj + 3) * 68 + c];
        *(u16x4*)(op + (size_t)(c0 + c) * R + r0 + 4 * rj) = o;
    }
}

// ---------------- router: logits -> softmax -> top2 -> renormalized gates
__global__ __launch_bounds__(256)
void router_k(const float* __restrict__ x, const float* __restrict__ rw,
              int* __restrict__ counts, int* __restrict__ tE,
              int* __restrict__ tS, float* __restrict__ tG) {
    int wave = threadIdx.x >> 6, lane = threadIdx.x & 63;
    int t = blockIdx.x * 4 + wave;
    const float* xr = x + (size_t)t * DIM;
    float xv[16];
#pragma unroll
    for (int i = 0; i < 16; ++i) xv[i] = xr[lane + 64*i];
    float lg[NEXP];
#pragma unroll
    for (int e = 0; e < NEXP; ++e) {
        const float* wr_ = rw + e * DIM;
        float a = 0.f;
#pragma unroll
        for (int i = 0; i < 16; ++i) a += xv[i] * wr_[lane + 64*i];
        lg[e] = a;
    }
#pragma unroll
    for (int off = 32; off > 0; off >>= 1)
#pragma unroll
        for (int e = 0; e < NEXP; ++e) lg[e] += __shfl_xor(lg[e], off, 64);
    if (lane == 0) {
        float mx = lg[0];
        for (int e = 1; e < NEXP; ++e) mx = fmaxf(mx, lg[e]);
        float p[NEXP], s = 0.f;
        for (int e = 0; e < NEXP; ++e) { p[e] = expf(lg[e] - mx); s += p[e]; }
        float inv_s = 1.f / s;
        for (int e = 0; e < NEXP; ++e) p[e] *= inv_s;
        int i0 = 0;
        for (int e = 1; e < NEXP; ++e) if (p[e] > p[i0]) i0 = e;
        int i1 = (i0 == 0) ? 1 : 0;
        for (int e = 0; e < NEXP; ++e) if (e != i0 && p[e] > p[i1]) i1 = e;
        float v0 = p[i0], v1 = p[i1];
        float inv = 1.f / (v0 + v1 + 1e-9f);
        int s0 = atomicAdd(&counts[i0], 1);
        int s1 = atomicAdd(&counts[i1], 1);
        tE[2*t] = i0;  tE[2*t+1] = i1;
        tS[2*t] = s0;  tS[2*t+1] = s1;
        tG[2*t] = v0 * inv;  tG[2*t+1] = v1 * inv;
    }
}

// inline exclusive scan of 128-padded counts: returns base for expert e
__device__ __forceinline__ int pbase_of(const int* __restrict__ counts, int e) {
    int pb = 0;
#pragma unroll
    for (int i = 0; i < NEXP; ++i) {
        int pad = ((counts[i] + 127) >> 7) << 7;
        pb += (i < e) ? pad : 0;
    }
    return pb;
}

// ---------------- gather x rows (fp32) into packed bf16 rows per assignment
__global__ __launch_bounds__(256)
void gather_k(const float* __restrict__ x, const int* __restrict__ tE,
              const int* __restrict__ tS, const int* __restrict__ counts,
              u16* __restrict__ xg) {
    int a = blockIdx.x;              // 0..8191
    int t = a >> 1, k = a & 1;
    int e = tE[2*t + k];
    int row = pbase_of(counts, e) + tS[2*t + k];
    const f32x4* xr = (const f32x4*)(x + (size_t)t * DIM);
    u16x4* o = (u16x4*)(xg + (size_t)row * DIM);
    int i = threadIdx.x;             // 256 threads x 4 floats = 1024
    f32x4 v = xr[i];
    u16x4 r; r.x = f2bf(v.x); r.y = f2bf(v.y); r.z = f2bf(v.z); r.w = f2bf(v.w);
    o[i] = r;
}

// ---------------- grouped GEMM: C[row][col] = A[row][K_sub] * Bt[col][K_sub]  (per expert)
// m97 structure: 128x128 tile, BK=64, 4 waves, 4x4 of mfma_f32_16x16x32_bf16,
// global_load_lds width-16 staging, XOR-swizzled LDS (conflict-free, r3-verified).
// Grid is sized to the statistical row maximum (10 x 128 = 1280 rows/expert,
// counts ~1024+-42 so +6 sigma): cuts early-exit dispatch churn 4x vs mt=32.
template<int K, int KSPLIT, bool GELU, typename OutT>
__global__ __launch_bounds__(256)
void gemm_bt(const u16* __restrict__ A, const u16* __restrict__ BtAll,
             OutT* __restrict__ C, const int* __restrict__ counts,
             int N, size_t cstride) {
    int e  = blockIdx.z / KSPLIT;
    int ks = blockIdx.z % KSPLIT;
    int cnt = counts[e];
    int mt = blockIdx.y;
    if (mt * 128 >= cnt) return;
    int row0 = pbase_of(counts, e) + mt * 128;
    const u16* Bt = BtAll + (size_t)e * N * K;
    OutT* Cp = C + (size_t)ks * cstride;
    int col0 = blockIdx.x * 128;
    const int kb0 = ks * (K / KSPLIT);
    constexpr int KITER = K / KSPLIT / 64;

    __shared__ __align__(16) u16 smem[128 * 128];   // As=[0,8K) Bs=[8K,16K); epilogue reuses 32 KB
    u16* As = smem;
    u16* Bs = smem + 128 * 64;

    int tid = threadIdx.x;
    int lane = tid & 63;
    int w = tid >> 6;
    int quad = lane >> 4, m16 = lane & 15;
    int wr = (w >> 1) * 64, wc = (w & 1) * 64;
    int rsub = lane >> 3;      // 0..7: row within an 8-row staging group
    int kch  = lane & 7;       // 16B chunk within row (LDS slot)
    int kchs = kch ^ rsub;     // swizzled GLOBAL chunk fetched into that slot

    // hoisted staging pointers (bumped +64 elem = 128 B per K-iter)
    const u16* ga[4];
    const u16* gb[4];
#pragma unroll
    for (int i = 0; i < 4; ++i) {
        int r = (w * 4 + i) * 8 + rsub;
        ga[i] = A  + (size_t)(row0 + r) * K + kb0 + kchs * 8;
        gb[i] = Bt + (size_t)(col0 + r) * K + kb0 + kchs * 8;
    }
    // hoisted fragment read bases; mi adds compile-time 1024-elem (2048 B) offsets
    int sw = m16 & 7;
    const u16* aP0 = As + (wr + m16) * 64 + ((quad       ^ sw) << 3);
    const u16* aP1 = As + (wr + m16) * 64 + (((4 + quad) ^ sw) << 3);
    const u16* bP0 = Bs + (wc + m16) * 64 + ((quad       ^ sw) << 3);
    const u16* bP1 = Bs + (wc + m16) * 64 + (((4 + quad) ^ sw) << 3);

    f32x4 acc[4][4] = {};

    for (int kit = 0; kit < KITER; ++kit) {
#pragma unroll
        for (int i = 0; i < 4; ++i) {
            int grp = w * 4 + i;
            __builtin_amdgcn_global_load_lds((gbl_uint*)ga[i], (lds_uint*)(As + grp * 512), 16, 0, 0);
            __builtin_amdgcn_global_load_lds((gbl_uint*)gb[i], (lds_uint*)(Bs + grp * 512), 16, 0, 0);
            ga[i] += 64; gb[i] += 64;
        }
        __syncthreads();
        {
            short8 af[4], bfr[4];
#pragma unroll
            for (int mi = 0; mi < 4; ++mi) af[mi]  = *(const short8*)(aP0 + mi * 1024);
#pragma unroll
            for (int ni = 0; ni < 4; ++ni) bfr[ni] = *(const short8*)(bP0 + ni * 1024);
#pragma unroll
            for (int mi = 0; mi < 4; ++mi)
#pragma unroll
                for (int ni = 0; ni < 4; ++ni)
                    acc[mi][ni] = __builtin_amdgcn_mfma_f32_16x16x32_bf16(af[mi], bfr[ni], acc[mi][ni], 0, 0, 0);
#pragma unroll
            for (int mi = 0; mi < 4; ++mi) af[mi]  = *(const short8*)(aP1 + mi * 1024);
#pragma unroll
            for (int ni = 0; ni < 4; ++ni) bfr[ni] = *(const short8*)(bP1 + ni * 1024);
#pragma unroll
            for (int mi = 0; mi < 4; ++mi)
#pragma unroll
                for (int ni = 0; ni < 4; ++ni)
                    acc[mi][ni] = __builtin_amdgcn_mfma_f32_16x16x32_bf16(af[mi], bfr[ni], acc[mi][ni], 0, 0, 0);
        }
        __syncthreads();
    }

    // epilogue: C/D layout col=lane&15, row=quad*4+reg
    if (GELU) {
        // stage bf16 tile in LDS (XOR-swizzled 16B chunks), then coalesced u16x8 stores
#pragma unroll
        for (int mi = 0; mi < 4; ++mi) {
#pragma unroll
            for (int r = 0; r < 4; ++r) {
                int row = wr + mi * 16 + quad * 4 + r;
#pragma unroll
                for (int ni = 0; ni < 4; ++ni) {
                    int col = wc + ni * 16 + m16;
                    int c16 = col >> 3, w8 = col & 7;
                    smem[row * 128 + (((c16 ^ (row & 15)) << 3) | w8)] = f2bf(gelu_f(acc[mi][ni][r]));
                }
            }
        }
        __syncthreads();
        int row_b = tid >> 4, c16_b = tid & 15;
        const u16* ls = smem + row_b * 128 + (((c16_b ^ (row_b & 15)) << 3));
        u16* gp = (u16*)Cp + (size_t)(row0 + row_b) * N + col0 + c16_b * 8;
#pragma unroll
        for (int j = 0; j < 8; ++j) {
            *(u16x8*)gp = *(const u16x8*)ls;
            ls += 16 * 128;
            gp += (size_t)16 * N;
        }
    } else {
        float* gp = (float*)Cp + (size_t)(row0 + wr + quad * 4) * N + col0 + wc + m16;
#pragma unroll
        for (int mi = 0; mi < 4; ++mi)
#pragma unroll
            for (int r = 0; r < 4; ++r) {
                float* rp = gp + (size_t)(mi * 16 + r) * N;
#pragma unroll
                for (int ni = 0; ni < 4; ++ni)
                    rp[ni * 16] = acc[mi][ni][r];
            }
    }
}

// ---------------- combine: out[t] = g0*(p0+p1)[row0(t)] + g1*(p0+p1)[row1(t)]
__global__ __launch_bounds__(256)
void combine_k(const float* __restrict__ p0, const float* __restrict__ p1,
               const int* __restrict__ tE, const int* __restrict__ tS,
               const float* __restrict__ tG, const int* __restrict__ counts,
               float* __restrict__ out) {
    int t = blockIdx.x;
    int e0 = tE[2*t], e1 = tE[2*t+1];
    int r0 = pbase_of(counts, e0) + tS[2*t];
    int r1 = pbase_of(counts, e1) + tS[2*t+1];
    float g0 = tG[2*t], g1 = tG[2*t+1];
    int i = threadIdx.x;
    f32x4 a0 = ((const f32x4*)(p0 + (size_t)r0 * DIM))[i];
    f32x4 b0 = ((const f32x4*)(p1 + (size_t)r0 * DIM))[i];
    f32x4 a1 = ((const f32x4*)(p0 + (size_t)r1 * DIM))[i];
    f32x4 b1 = ((const f32x4*)(p1 + (size_t)r1 * DIM))[i];
    f32x4* o = (f32x4*)(out + (size_t)t * DIM);
    o[i] = g0 * (a0 + b0) + g1 * (a1 + b1);
}

extern "C" void kernel_launch(void* const* d_in, const int* in_sizes, int n_in,
                              void* d_out, int out_size, void* d_ws, size_t ws_size,
                              hipStream_t stream) {
    const float* x  = (const float*)d_in[0];   // [4096,1024]
    const float* rw = (const float*)d_in[1];   // [8,1024]
    const float* w1 = (const float*)d_in[2];   // [8,1024,4096]
    const float* w2 = (const float*)d_in[3];   // [8,4096,1024]
    float* out = (float*)d_out;

    char* ws = (char*)d_ws;
    // layout (bytes):
    u16* w1t = (u16*)(ws + 0);                 // bf16 [E][H][D]   67,108,864
    u16* xg  = (u16*)(ws + 67108864ull);       // bf16 [9216][D]   18,874,368 -> 85,983,232
    u16* w2t = (u16*)(ws + 85983232ull);       // bf16 [E][D][H]   67,108,864 -> 153,092,096
    u16* hb  = (u16*)(ws + 153092096ull);      // bf16 [9216][H]   75,497,472 -> 228,589,568
    // fc2 split-K partials alias w1t+xg (dead after fc1): 2 x 37,748,736 = 75,497,472 <= 85,983,232
    float* p0 = (float*)(ws + 0);
    float* p1 = (float*)(ws + 37748736ull);
    int* ctrl   = (int*)(ws + 228589568ull);
    int* counts = ctrl;            // 8
    int* tE     = ctrl + 32;       // 8192
    int* tS     = ctrl + 32 + 8192;
    float* tG   = (float*)(ctrl + 32 + 16384);

    // fused transposes (+ counts zeroing, block 0)
    transpose_cast2<<<16384, 256, 0, stream>>>(w1, w1t, w2, w2t, counts);
    router_k<<<T_TOK / 4, 256, 0, stream>>>(x, rw, counts, tE, tS, tG);
    gather_k<<<T_TOK * 2, 256, 0, stream>>>(x, tE, tS, counts, xg);
    // fc1 + gelu: [rows x 1024] @ [1024 x 4096] -> hb (bf16).
    // mt extent 10 (1280 rows/expert, +6 sigma) instead of 32: 4x less dispatch churn.
    gemm_bt<DIM, 1, true, u16><<<dim3(HID / 128, 10, NEXP), 256, 0, stream>>>(
        xg, w1t, hb, counts, HID, 0);
    // fc2 split-K=2: [rows x 4096] @ [4096 x 1024] -> p0/p1 (f32)
    gemm_bt<HID, 2, false, float><<<dim3(DIM / 128, 10, NEXP * 2), 256, 0, stream>>>(
        hb, w2t, p0, counts, DIM, (size_t)MAXROWS * DIM);
    combine_k<<<T_TOK, 256, 0, stream>>>(p0, p1, tE, tS, tG, counts, out);
}

// Round 5
// 645.362 us; speedup vs baseline: 1.1369x; 1.0393x over previous
//
#include <hip/hip_runtime.h>

// Problem constants: B=2, S=2048 -> T=4096 tokens; D=1024, H=4096, E=8, top-2.
#define T_TOK 4096
#define DIM   1024
#define HID   4096
#define NEXP  8
#define MAXROWS 9216

typedef unsigned short u16;
typedef __attribute__((ext_vector_type(8))) short short8;   // 8 bf16 (4 VGPRs) MFMA frag
typedef __attribute__((ext_vector_type(4))) float f32x4;
typedef __attribute__((ext_vector_type(4))) unsigned short u16x4;
typedef __attribute__((ext_vector_type(8))) unsigned short u16x8;

typedef __attribute__((address_space(3))) unsigned int lds_uint;
typedef const __attribute__((address_space(1))) unsigned int gbl_uint;

__device__ __forceinline__ u16 f2bf(float f) {
    union { float f; unsigned int u; } v; v.f = f;
    unsigned int r = v.u + 0x7fffu + ((v.u >> 16) & 1u);   // RNE
    return (u16)(r >> 16);
}

// fast gelu (tanh form): max |err| vs exact erf-gelu ~3e-4, well under budget
__device__ __forceinline__ float gelu_f(float v) {
    float u = 1.5957691216f * (v + 0.044715f * v * v * v);   // 2*0.7978845608*(...)
    float s = 1.0f / (1.0f + __expf(-u));                    // sigmoid(2u') == 0.5*(1+tanh(u'))
    return v * s;
}

// ---------------- blocked transpose+cast for BOTH weights; also zeroes counts.
// fp32 [K][N] per expert -> bf16 BLOCKED tiles: [e][ct][kt][128n x 64k] (8192 elems
// contiguous per tile). tile(ct,kt)[n][k] = w[e][kt*64+k][ct*128+n].
// Writes are fully sequential 16KB runs (1KB/wave/iter) vs the old 128B segments.
// blockIdx.x in [0,8192): first 4096 blocks w1 (K=1024,N=4096,KT=16,CT=32);
// rest w2 (K=4096,N=1024,KT=64,CT=8). 512 tiles per expert either way.
__global__ __launch_bounds__(256)
void transpose_blocked(const float* __restrict__ w1, u16* __restrict__ w1t,
                       const float* __restrict__ w2, u16* __restrict__ w2t,
                       int* __restrict__ counts) {
    int b = blockIdx.x;
    if (b == 0 && threadIdx.x < NEXP) counts[threadIdx.x] = 0;
    const float* in; u16* out; int C, KT, ct, kt, e;
    if (b < 4096) {
        e = b >> 9; int t = b & 511; ct = t & 31; kt = t >> 5;   // CT=32, KT=16
        in = w1; out = w1t; C = HID; KT = 16;
    } else {
        b -= 4096;
        e = b >> 9; int t = b & 511; ct = t & 7; kt = t >> 3;    // CT=8, KT=64
        in = w2; out = w2t; C = DIM; KT = 64;
    }
    __shared__ u16 tl[64 * 130];   // [k=64][n=128 +2 pad]; 65-dword rows -> odd stride,
                                   // column walks land on distinct banks
    size_t mo = (size_t)e * DIM * HID;
    const float* ip = in + mo + (size_t)(kt * 64) * C + ct * 128;
    u16* op = out + mo + (size_t)(ct * KT + kt) * 8192;
    int tid = threadIdx.x;
#pragma unroll
    for (int j = 0; j < 8; ++j) {
        int id = tid + 256 * j;
        int kr = id >> 5, cg = id & 31;                          // k-row, 16B col-group
        f32x4 v = *(const f32x4*)(ip + (size_t)kr * C + 4 * cg);
        u16x4 w; w.x = f2bf(v.x); w.y = f2bf(v.y); w.z = f2bf(v.z); w.w = f2bf(v.w);
        *(u16x4*)(tl + kr * 130 + 4 * cg) = w;
    }
    __syncthreads();
#pragma unroll
    for (int j = 0; j < 4; ++j) {
        int id = tid + 256 * j;
        int n = id >> 3, c = id & 7;                             // out row n, 16B k-chunk
        u16x8 o;
#pragma unroll
        for (int m = 0; m < 8; ++m) o[m] = tl[(c * 8 + m) * 130 + n];
        *(u16x8*)(op + id * 8) = o;                              // offset n*64+c*8 == id*8
    }
}

// ---------------- router: logits -> softmax -> top2 -> renormalized gates
__global__ __launch_bounds__(256)
void router_k(const float* __restrict__ x, const float* __restrict__ rw,
              int* __restrict__ counts, int* __restrict__ tE,
              int* __restrict__ tS, float* __restrict__ tG) {
    int wave = threadIdx.x >> 6, lane = threadIdx.x & 63;
    int t = blockIdx.x * 4 + wave;
    const float* xr = x + (size_t)t * DIM;
    float xv[16];
#pragma unroll
    for (int i = 0; i < 16; ++i) xv[i] = xr[lane + 64*i];
    float lg[NEXP];
#pragma unroll
    for (int e = 0; e < NEXP; ++e) {
        const float* wr_ = rw + e * DIM;
        float a = 0.f;
#pragma unroll
        for (int i = 0; i < 16; ++i) a += xv[i] * wr_[lane + 64*i];
        lg[e] = a;
    }
#pragma unroll
    for (int off = 32; off > 0; off >>= 1)
#pragma unroll
        for (int e = 0; e < NEXP; ++e) lg[e] += __shfl_xor(lg[e], off, 64);
    if (lane == 0) {
        float mx = lg[0];
        for (int e = 1; e < NEXP; ++e) mx = fmaxf(mx, lg[e]);
        float p[NEXP], s = 0.f;
        for (int e = 0; e < NEXP; ++e) { p[e] = expf(lg[e] - mx); s += p[e]; }
        float inv_s = 1.f / s;
        for (int e = 0; e < NEXP; ++e) p[e] *= inv_s;
        int i0 = 0;
        for (int e = 1; e < NEXP; ++e) if (p[e] > p[i0]) i0 = e;
        int i1 = (i0 == 0) ? 1 : 0;
        for (int e = 0; e < NEXP; ++e) if (e != i0 && p[e] > p[i1]) i1 = e;
        float v0 = p[i0], v1 = p[i1];
        float inv = 1.f / (v0 + v1 + 1e-9f);
        int s0 = atomicAdd(&counts[i0], 1);
        int s1 = atomicAdd(&counts[i1], 1);
        tE[2*t] = i0;  tE[2*t+1] = i1;
        tS[2*t] = s0;  tS[2*t+1] = s1;
        tG[2*t] = v0 * inv;  tG[2*t+1] = v1 * inv;
    }
}

// inline exclusive scan of 128-padded counts: returns base for expert e
__device__ __forceinline__ int pbase_of(const int* __restrict__ counts, int e) {
    int pb = 0;
#pragma unroll
    for (int i = 0; i < NEXP; ++i) {
        int pad = ((counts[i] + 127) >> 7) << 7;
        pb += (i < e) ? pad : 0;
    }
    return pb;
}

// ---------------- gather x rows (fp32) into packed bf16 rows per assignment
__global__ __launch_bounds__(256)
void gather_k(const float* __restrict__ x, const int* __restrict__ tE,
              const int* __restrict__ tS, const int* __restrict__ counts,
              u16* __restrict__ xg) {
    int a = blockIdx.x;              // 0..8191
    int t = a >> 1, k = a & 1;
    int e = tE[2*t + k];
    int row = pbase_of(counts, e) + tS[2*t + k];
    const f32x4* xr = (const f32x4*)(x + (size_t)t * DIM);
    u16x4* o = (u16x4*)(xg + (size_t)row * DIM);
    int i = threadIdx.x;             // 256 threads x 4 floats = 1024
    f32x4 v = xr[i];
    u16x4 r; r.x = f2bf(v.x); r.y = f2bf(v.y); r.z = f2bf(v.z); r.w = f2bf(v.w);
    o[i] = r;
}

// ---------------- grouped GEMM: C[row][col] = A[row][K_sub] * B[K_sub][col]  (per expert)
// m97 structure: 128x128 tile, BK=64, 4 waves, 4x4 of mfma_f32_16x16x32_bf16,
// global_load_lds width-16 staging, XOR-swizzled LDS (conflict-free, verified).
// B is consumed from the BLOCKED layout ([ct][kt][128x64] tiles): gb walks +8192/iter.
// Expert-per-XCD swizzle: 1D grid, e = lin&7 (heuristic lin%8 -> XCD), mt slowest
// within an XCD so col-tiles sharing an A row-block run together (A 256KB L2-hot,
// B panel streamed once per mt round from XCD-local L2/L3).
template<int K, int KSPLIT, int NX, bool GELU, typename OutT>
__global__ __launch_bounds__(256)
void gemm_bt(const u16* __restrict__ A, const u16* __restrict__ BtAll,
             OutT* __restrict__ C, const int* __restrict__ counts,
             int N, size_t cstride) {
    int lin = blockIdx.x;
    int e = lin & 7;                     // XCD-aligned expert
    int kk = lin >> 3;
    int ct = kk % NX;                    // NX is pow2
    int rest = kk / NX;
    int ks = rest % KSPLIT;
    int mt = rest / KSPLIT;
    int cnt = counts[e];
    if (mt * 128 >= cnt) return;
    int row0 = pbase_of(counts, e) + mt * 128;
    const u16* Bt = BtAll + (size_t)e * N * K;
    OutT* Cp = C + (size_t)ks * cstride;
    int col0 = ct * 128;
    const int kb0 = ks * (K / KSPLIT);
    constexpr int KT = K / 64;           // total k-tiles per expert (blocked layout)
    constexpr int KITER = K / KSPLIT / 64;

    __shared__ __align__(16) u16 smem[128 * 128];   // As=[0,8K) Bs=[8K,16K); epilogue reuses 32 KB
    u16* As = smem;
    u16* Bs = smem + 128 * 64;

    int tid = threadIdx.x;
    int lane = tid & 63;
    int w = tid >> 6;
    int quad = lane >> 4, m16 = lane & 15;
    int wr = (w >> 1) * 64, wc = (w & 1) * 64;
    int rsub = lane >> 3;      // 0..7: row within an 8-row staging group
    int kch  = lane & 7;       // 16B chunk within row (LDS slot)
    int kchs = kch ^ rsub;     // swizzled GLOBAL chunk fetched into that slot

    // hoisted staging pointers; A bumps +64 elem (row-major [row][K]),
    // B bumps +8192 elem (next 128x64 blocked tile)
    const u16* ga[4];
    const u16* gb[4];
#pragma unroll
    for (int i = 0; i < 4; ++i) {
        int r = (w * 4 + i) * 8 + rsub;
        ga[i] = A  + (size_t)(row0 + r) * K + kb0 + kchs * 8;
        gb[i] = Bt + ((size_t)ct * KT + kb0 / 64) * 8192 + r * 64 + kchs * 8;
    }
    // hoisted fragment read bases; mi adds compile-time 1024-elem (2048 B) offsets
    int sw = m16 & 7;
    const u16* aP0 = As + (wr + m16) * 64 + ((quad       ^ sw) << 3);
    const u16* aP1 = As + (wr + m16) * 64 + (((4 + quad) ^ sw) << 3);
    const u16* bP0 = Bs + (wc + m16) * 64 + ((quad       ^ sw) << 3);
    const u16* bP1 = Bs + (wc + m16) * 64 + (((4 + quad) ^ sw) << 3);

    f32x4 acc[4][4] = {};

    for (int kit = 0; kit < KITER; ++kit) {
#pragma unroll
        for (int i = 0; i < 4; ++i) {
            int grp = w * 4 + i;
            __builtin_amdgcn_global_load_lds((gbl_uint*)ga[i], (lds_uint*)(As + grp * 512), 16, 0, 0);
            __builtin_amdgcn_global_load_lds((gbl_uint*)gb[i], (lds_uint*)(Bs + grp * 512), 16, 0, 0);
            ga[i] += 64; gb[i] += 8192;
        }
        __syncthreads();
        {
            short8 af[4], bfr[4];
#pragma unroll
            for (int mi = 0; mi < 4; ++mi) af[mi]  = *(const short8*)(aP0 + mi * 1024);
#pragma unroll
            for (int ni = 0; ni < 4; ++ni) bfr[ni] = *(const short8*)(bP0 + ni * 1024);
#pragma unroll
            for (int mi = 0; mi < 4; ++mi)
#pragma unroll
                for (int ni = 0; ni < 4; ++ni)
                    acc[mi][ni] = __builtin_amdgcn_mfma_f32_16x16x32_bf16(af[mi], bfr[ni], acc[mi][ni], 0, 0, 0);
#pragma unroll
            for (int mi = 0; mi < 4; ++mi) af[mi]  = *(const short8*)(aP1 + mi * 1024);
#pragma unroll
            for (int ni = 0; ni < 4; ++ni) bfr[ni] = *(const short8*)(bP1 + ni * 1024);
#pragma unroll
            for (int mi = 0; mi < 4; ++mi)
#pragma unroll
                for (int ni = 0; ni < 4; ++ni)
                    acc[mi][ni] = __builtin_amdgcn_mfma_f32_16x16x32_bf16(af[mi], bfr[ni], acc[mi][ni], 0, 0, 0);
        }
        __syncthreads();
    }

    // epilogue: C/D layout col=lane&15, row=quad*4+reg
    if (GELU) {
        // stage bf16 tile in LDS (XOR-swizzled 16B chunks), then coalesced u16x8 stores
#pragma unroll
        for (int mi = 0; mi < 4; ++mi) {
#pragma unroll
            for (int r = 0; r < 4; ++r) {
                int row = wr + mi * 16 + quad * 4 + r;
#pragma unroll
                for (int ni = 0; ni < 4; ++ni) {
                    int col = wc + ni * 16 + m16;
                    int c16 = col >> 3, w8 = col & 7;
                    smem[row * 128 + (((c16 ^ (row & 15)) << 3) | w8)] = f2bf(gelu_f(acc[mi][ni][r]));
                }
            }
        }
        __syncthreads();
        int row_b = tid >> 4, c16_b = tid & 15;
        const u16* ls = smem + row_b * 128 + (((c16_b ^ (row_b & 15)) << 3));
        u16* gp = (u16*)Cp + (size_t)(row0 + row_b) * N + col0 + c16_b * 8;
#pragma unroll
        for (int j = 0; j < 8; ++j) {
            *(u16x8*)gp = *(const u16x8*)ls;
            ls += 16 * 128;
            gp += (size_t)16 * N;
        }
    } else {
        float* gp = (float*)Cp + (size_t)(row0 + wr + quad * 4) * N + col0 + wc + m16;
#pragma unroll
        for (int mi = 0; mi < 4; ++mi)
#pragma unroll
            for (int r = 0; r < 4; ++r) {
                float* rp = gp + (size_t)(mi * 16 + r) * N;
#pragma unroll
                for (int ni = 0; ni < 4; ++ni)
                    rp[ni * 16] = acc[mi][ni][r];
            }
    }
}

// ---------------- combine: out[t] = g0*(p0+p1)[row0(t)] + g1*(p0+p1)[row1(t)]
__global__ __launch_bounds__(256)
void combine_k(const float* __restrict__ p0, const float* __restrict__ p1,
               const int* __restrict__ tE, const int* __restrict__ tS,
               const float* __restrict__ tG, const int* __restrict__ counts,
               float* __restrict__ out) {
    int t = blockIdx.x;
    int e0 = tE[2*t], e1 = tE[2*t+1];
    int r0 = pbase_of(counts, e0) + tS[2*t];
    int r1 = pbase_of(counts, e1) + tS[2*t+1];
    float g0 = tG[2*t], g1 = tG[2*t+1];
    int i = threadIdx.x;
    f32x4 a0 = ((const f32x4*)(p0 + (size_t)r0 * DIM))[i];
    f32x4 b0 = ((const f32x4*)(p1 + (size_t)r0 * DIM))[i];
    f32x4 a1 = ((const f32x4*)(p0 + (size_t)r1 * DIM))[i];
    f32x4 b1 = ((const f32x4*)(p1 + (size_t)r1 * DIM))[i];
    f32x4* o = (f32x4*)(out + (size_t)t * DIM);
    o[i] = g0 * (a0 + b0) + g1 * (a1 + b1);
}

extern "C" void kernel_launch(void* const* d_in, const int* in_sizes, int n_in,
                              void* d_out, int out_size, void* d_ws, size_t ws_size,
                              hipStream_t stream) {
    const float* x  = (const float*)d_in[0];   // [4096,1024]
    const float* rw = (const float*)d_in[1];   // [8,1024]
    const float* w1 = (const float*)d_in[2];   // [8,1024,4096]
    const float* w2 = (const float*)d_in[3];   // [8,4096,1024]
    float* out = (float*)d_out;

    char* ws = (char*)d_ws;
    // layout (bytes):
    u16* w1t = (u16*)(ws + 0);                 // bf16 blocked [E][512 tiles][8192]   67,108,864
    u16* xg  = (u16*)(ws + 67108864ull);       // bf16 [9216][D]   18,874,368 -> 85,983,232
    u16* w2t = (u16*)(ws + 85983232ull);       // bf16 blocked     67,108,864 -> 153,092,096
    u16* hb  = (u16*)(ws + 153092096ull);      // bf16 [9216][H]   75,497,472 -> 228,589,568
    // fc2 split-K partials alias w1t+xg (dead after fc1): 2 x 37,748,736 = 75,497,472 <= 85,983,232
    float* p0 = (float*)(ws + 0);
    float* p1 = (float*)(ws + 37748736ull);
    int* ctrl   = (int*)(ws + 228589568ull);
    int* counts = ctrl;            // 8
    int* tE     = ctrl + 32;       // 8192
    int* tS     = ctrl + 32 + 8192;
    float* tG   = (float*)(ctrl + 32 + 16384);

    // blocked transposes (+ counts zeroing, block 0)
    transpose_blocked<<<8192, 256, 0, stream>>>(w1, w1t, w2, w2t, counts);
    router_k<<<T_TOK / 4, 256, 0, stream>>>(x, rw, counts, tE, tS, tG);
    gather_k<<<T_TOK * 2, 256, 0, stream>>>(x, tE, tS, counts, xg);
    // fc1 + gelu: [rows x 1024] @ [1024 x 4096] -> hb (bf16).
    // 1D grid: 8e x (32ct x 10mt) = 2560, e = lin&7 (expert-per-XCD)
    gemm_bt<DIM, 1, 32, true, u16><<<2560, 256, 0, stream>>>(
        xg, w1t, hb, counts, HID, 0);
    // fc2 split-K=2: [rows x 4096] @ [4096 x 1024] -> p0/p1 (f32).
    // 1D grid: 8e x (8ct x 2ks x 10mt) = 1280
    gemm_bt<HID, 2, 8, false, float><<<1280, 256, 0, stream>>>(
        hb, w2t, p0, counts, DIM, (size_t)MAXROWS * DIM);
    combine_k<<<T_TOK, 256, 0, stream>>>(p0, p1, tE, tS, tG, counts, out);
}